// Round 6
// baseline (323.659 us; speedup 1.0000x reference)
//
#include <hip/hip_runtime.h>
#include <stdint.h>
#include <stddef.h>

// ---------------------------------------------------------------------------
// QuantizedLinear: y = x @ (scale*(Wq - zp))^T + bias
// GEMM view: M=8192, N=4096, K=4096.
// R6: 128x128 tile, BK=64, 256 threads (4 waves, 2x2, wave=64x64), dbuf LDS
// 64KiB -> 2 BLOCKS/CU (independent barriers => cross-block DS/MFMA overlap).
// Per K-tile: {8 ds_read ks0 -> stage ALL of t+1 (8 gld) -> 8 ds_read ks1 ->
// lgkm(8)+16 MFMA -> lgkm(0)+16 MFMA -> VMCNT(0)+barrier}. One barrier and
// one vmcnt per tile; full-tile prefetch cover. 3-bit chunk-XOR swizzle
// (c ^= row&7) both-sides (rule #21). XCD block swizzle. Prepasses as R1.
// ---------------------------------------------------------------------------

typedef __attribute__((ext_vector_type(4))) float   f32x4;
typedef __attribute__((ext_vector_type(8))) short   short8;   // 8 x bf16
typedef __attribute__((ext_vector_type(4))) int     i32x4;
typedef __attribute__((ext_vector_type(8))) unsigned short ushort8;
typedef __attribute__((ext_vector_type(4))) unsigned short ushort4v;

__device__ __forceinline__ unsigned short f2bf(float f) {
  union { float f; unsigned u; } v; v.f = f;
  unsigned u = v.u;
  u += 0x7fffu + ((u >> 16) & 1u);      // RNE to bf16
  return (unsigned short)(u >> 16);
}

__device__ __forceinline__ void gld_lds16(const void* g, void* l) {
  __builtin_amdgcn_global_load_lds(
      (const __attribute__((address_space(1))) unsigned int*)g,
      (__attribute__((address_space(3))) unsigned int*)l,
      16, 0, 0);
}

__device__ __forceinline__ unsigned ldsAddr(const void* p) {
  return (unsigned)(size_t)(const __attribute__((address_space(3))) void*)p;
}

__device__ __forceinline__ void wgb() {
  asm volatile("" ::: "memory");
  __builtin_amdgcn_s_barrier();
  asm volatile("" ::: "memory");
}

#define DSR(dst, addr, OFF) \
  asm volatile("ds_read_b128 %0, %1 offset:" #OFF : "=v"(dst) : "v"(addr))
#define LGKM(N) do { asm volatile("s_waitcnt lgkmcnt(" #N ")" ::: "memory"); \
                     __builtin_amdgcn_sched_barrier(0); } while (0)
#define VMCNT(N) asm volatile("s_waitcnt vmcnt(" #N ")" ::: "memory")

// ---------- prepass: x fp32 -> bf16 ----------
__global__ __launch_bounds__(256) void cvt_x_kernel(
    const f32x4* __restrict__ x, ushort8* __restrict__ o, int n8) {
  int i = blockIdx.x * 256 + threadIdx.x;
  if (i >= n8) return;
  f32x4 a = x[2 * i], b = x[2 * i + 1];
  ushort8 r;
  r[0] = f2bf(a[0]); r[1] = f2bf(a[1]); r[2] = f2bf(a[2]); r[3] = f2bf(a[3]);
  r[4] = f2bf(b[0]); r[5] = f2bf(b[1]); r[6] = f2bf(b[2]); r[7] = f2bf(b[3]);
  o[i] = r;
}

// ---------- prepass: Wq int32 -> bf16 of (q - zp) ----------
__global__ __launch_bounds__(256) void cvt_w_kernel(
    const i32x4* __restrict__ q, ushort8* __restrict__ o,
    const float* __restrict__ zp_p, int n8) {
  int i = blockIdx.x * 256 + threadIdx.x;
  if (i >= n8) return;
  float zp = zp_p[0];
  i32x4 a = q[2 * i], b = q[2 * i + 1];
  ushort8 r;
  r[0] = f2bf((float)a[0] - zp); r[1] = f2bf((float)a[1] - zp);
  r[2] = f2bf((float)a[2] - zp); r[3] = f2bf((float)a[3] - zp);
  r[4] = f2bf((float)b[0] - zp); r[5] = f2bf((float)b[1] - zp);
  r[6] = f2bf((float)b[2] - zp); r[7] = f2bf((float)b[3] - zp);
  o[i] = r;
}

// ---------------------------------------------------------------------------
// Main 128^2 GEMM, 2 blocks/CU, 1-barrier-per-K-tile pipeline.
// LDS region (buf): A,B each [128 rows][64 k] bf16 = 16 KiB, staged linearly;
// logical 16B-chunk c (8/row) of row r stored at chunk position c ^ (r&7).
// ---------------------------------------------------------------------------
__global__ __launch_bounds__(256, 2) void qgemm128_kernel(
    const unsigned short* __restrict__ A,   // [M][K] bf16 (x)
    const unsigned short* __restrict__ B,   // [N][K] bf16 (dequant W)
    const float* __restrict__ bias, const float* __restrict__ scale_p,
    float* __restrict__ C, int M, int N, int K) {
  __shared__ __attribute__((aligned(16))) unsigned short sA[2 * 8192];  // 32 KiB
  __shared__ __attribute__((aligned(16))) unsigned short sB[2 * 8192];  // 32 KiB

  const int tid  = threadIdx.x;
  const int lane = tid & 63;
  const int w    = tid >> 6;         // 0..3
  const int wr   = w >> 1;           // 0..1  (M strip of 64)
  const int wc   = w & 1;            // 0..1  (N strip of 64)

  // XCD-aware block swizzle (bijective when nwg % 8 == 0)
  const int nwg = gridDim.x;
  const int bid = blockIdx.x;
  const int swz = ((nwg & 7) == 0) ? ((bid & 7) * (nwg >> 3) + (bid >> 3)) : bid;
  const int ntn = N >> 7;
  const int bm0 = (swz / ntn) << 7;
  const int bn0 = (swz % ntn) << 7;

  const int l16 = lane & 15;
  const int l4  = lane >> 4;                       // 0..3
  // read chunk (8 chunks/row): ks0 -> l4, ks1 -> 4+l4; swizzled by row&7=l16&7
  const int rchk0 = ((0 + l4) ^ (l16 & 7)) << 4;   // byte offset of chunk
  const int rchk1 = ((4 + l4) ^ (l16 & 7)) << 4;

  // per-lane LDS read byte bases within a 16 KiB region (row stride 128B)
  const unsigned aBase = (unsigned)((wr * 64 + l16) * 128);
  const unsigned bBase = (unsigned)((wc * 64 + l16) * 128);
  const unsigned sAaddr = ldsAddr(sA);
  const unsigned sBaddr = ldsAddr(sB);

  // staging: 1024 chunks/region; thread does chunks tid+256*i (i=0..3)
  // row_i = (tid>>3) + 32*i ; stored chunk pos = tid&7 ; src chunk = pos ^ (row&7)
  const int    r0   = tid >> 3;
  const int    srcoff = (((tid & 7) ^ ((tid >> 3) & 7)) << 3);  // src k-elems
  const unsigned short* Ab = A + (size_t)bm0 * K;
  const unsigned short* Bb = B + (size_t)bn0 * K;

  f32x4 acc[4][4] = {};
  const int nkt = K >> 6;

#define STAGE_A(NX, KOFF) do {                                              \
    unsigned short* _d = sA + ((NX) << 13);                                 \
    _Pragma("unroll")                                                       \
    for (int i = 0; i < 4; ++i)                                             \
      gld_lds16(Ab + (size_t)(r0 + 32 * i) * K + (KOFF) + srcoff,           \
                _d + ((i * 256 + tid) << 3));                               \
  } while (0)
#define STAGE_B(NX, KOFF) do {                                              \
    unsigned short* _d = sB + ((NX) << 13);                                 \
    _Pragma("unroll")                                                       \
    for (int i = 0; i < 4; ++i)                                             \
      gld_lds16(Bb + (size_t)(r0 + 32 * i) * K + (KOFF) + srcoff,           \
                _d + ((i * 256 + tid) << 3));                               \
  } while (0)

  // ---- prologue: stage tile0 ----
  STAGE_A(0, 0); STAGE_B(0, 0);
  VMCNT(0);
  wgb();

  for (int kt = 0; kt < nkt; ++kt) {
    const int cur = kt & 1, nx = cur ^ 1;
    const bool pf = (kt + 1 < nkt);
    const int kn = (kt + 1) << 6;

    const unsigned aR0 = sAaddr + (unsigned)(cur << 14) + aBase + rchk0;
    const unsigned bR0 = sBaddr + (unsigned)(cur << 14) + bBase + rchk0;
    const unsigned aR1 = sAaddr + (unsigned)(cur << 14) + aBase + rchk1;
    const unsigned bR1 = sBaddr + (unsigned)(cur << 14) + bBase + rchk1;

    short8 a[4], b[4], a2[4], b2[4];

    // ks0 reads (8)
    DSR(a[0], aR0, 0); DSR(a[1], aR0, 2048); DSR(a[2], aR0, 4096); DSR(a[3], aR0, 6144);
    DSR(b[0], bR0, 0); DSR(b[1], bR0, 2048); DSR(b[2], bR0, 4096); DSR(b[3], bR0, 6144);
    // stage ALL of tile t+1 (8 gld) -- max HBM cover, writes to nx (disjoint)
    if (pf) { STAGE_A(nx, kn); STAGE_B(nx, kn); }
    // ks1 reads (8) -- drain under ks0 MFMA
    DSR(a2[0], aR1, 0); DSR(a2[1], aR1, 2048); DSR(a2[2], aR1, 4096); DSR(a2[3], aR1, 6144);
    DSR(b2[0], bR1, 0); DSR(b2[1], bR1, 2048); DSR(b2[2], bR1, 4096); DSR(b2[3], bR1, 6144);

    LGKM(8);   // ks0 operands resident (DS completes in order)
    __builtin_amdgcn_s_setprio(1);
#pragma unroll
    for (int m = 0; m < 4; ++m)
#pragma unroll
      for (int n = 0; n < 4; ++n)
        acc[m][n] = __builtin_amdgcn_mfma_f32_16x16x32_bf16(a[m], b[n], acc[m][n], 0, 0, 0);
    __builtin_amdgcn_s_setprio(0);

    LGKM(0);   // ks1 operands resident
    __builtin_amdgcn_s_setprio(1);
#pragma unroll
    for (int m = 0; m < 4; ++m)
#pragma unroll
      for (int n = 0; n < 4; ++n)
        acc[m][n] = __builtin_amdgcn_mfma_f32_16x16x32_bf16(a2[m], b2[n], acc[m][n], 0, 0, 0);
    __builtin_amdgcn_s_setprio(0);

    // tile-end: t+1 resident for all waves + all waves done reading cur
    if (pf) { VMCNT(0); wgb(); }
  }
#undef STAGE_A
#undef STAGE_B

  // ---- epilogue: y = scale*acc + bias ----
  const float s = scale_p[0];
#pragma unroll
  for (int nf = 0; nf < 4; ++nf) {
    const int col = bn0 + wc * 64 + nf * 16 + l16;
    const float bv = bias[col];
#pragma unroll
    for (int mf = 0; mf < 4; ++mf) {
      const int row0 = bm0 + wr * 64 + mf * 16 + (l4 << 2);
#pragma unroll
      for (int j = 0; j < 4; ++j)
        C[(size_t)(row0 + j) * N + col] = fmaf(s, acc[mf][nf][j], bv);
    }
  }
}

// ---------------------------------------------------------------------------
// Fallback (no workspace): R1's fused 128^2 kernel.
// ---------------------------------------------------------------------------
__global__ __launch_bounds__(256) void qgemm_fused_kernel(
    const float* __restrict__ A, const int* __restrict__ B,
    const float* __restrict__ bias, const float* __restrict__ scale_p,
    const float* __restrict__ zp_p, float* __restrict__ C,
    int M, int N, int K) {
  constexpr int BK = 32;
  __shared__ unsigned short sAf[128 * BK];
  __shared__ unsigned short sBf[128 * BK];
  const int tid = threadIdx.x, lane = tid & 63, w = tid >> 6;
  const int wr = w >> 1, wc = w & 1;
  const int bm0 = blockIdx.y * 128, bn0 = blockIdx.x * 128;
  const int l16 = lane & 15, lk = (lane >> 4) << 3;
  const float zp = zp_p[0];
  f32x4 acc[4][4] = {};
  for (int k0 = 0; k0 < K; k0 += BK) {
#pragma unroll
    for (int c = 0; c < 4; ++c) {
      int ch = c * 256 + tid;
      int row = ch >> 3, c4 = (ch & 7) << 2;
      f32x4 av = *(const f32x4*)(A + (size_t)(bm0 + row) * K + k0 + c4);
      i32x4 bv = *(const i32x4*)(B + (size_t)(bn0 + row) * K + k0 + c4);
      ushort4v ra, rb;
      ra[0] = f2bf(av[0]); ra[1] = f2bf(av[1]); ra[2] = f2bf(av[2]); ra[3] = f2bf(av[3]);
      rb[0] = f2bf((float)bv[0] - zp); rb[1] = f2bf((float)bv[1] - zp);
      rb[2] = f2bf((float)bv[2] - zp); rb[3] = f2bf((float)bv[3] - zp);
      *(ushort4v*)&sAf[row * BK + c4] = ra;
      *(ushort4v*)&sBf[row * BK + c4] = rb;
    }
    __syncthreads();
    short8 a[4], b[4];
#pragma unroll
    for (int m = 0; m < 4; ++m) a[m] = *(const short8*)&sAf[(wr * 64 + m * 16 + l16) * BK + lk];
#pragma unroll
    for (int n = 0; n < 4; ++n) b[n] = *(const short8*)&sBf[(wc * 64 + n * 16 + l16) * BK + lk];
#pragma unroll
    for (int m = 0; m < 4; ++m)
#pragma unroll
      for (int n = 0; n < 4; ++n)
        acc[m][n] = __builtin_amdgcn_mfma_f32_16x16x32_bf16(a[m], b[n], acc[m][n], 0, 0, 0);
    __syncthreads();
  }
  const float s = scale_p[0];
#pragma unroll
  for (int n = 0; n < 4; ++n) {
    const int col = bn0 + wc * 64 + n * 16 + l16;
    const float bv = bias[col];
#pragma unroll
    for (int m = 0; m < 4; ++m) {
      const int row0 = bm0 + wr * 64 + m * 16 + ((lane >> 4) << 2);
#pragma unroll
      for (int j = 0; j < 4; ++j)
        C[(size_t)(row0 + j) * N + col] = fmaf(s, acc[m][n][j], bv);
    }
  }
}

extern "C" void kernel_launch(void* const* d_in, const int* in_sizes, int n_in,
                              void* d_out, int out_size, void* d_ws, size_t ws_size,
                              hipStream_t stream) {
  const float* x     = (const float*)d_in[0];
  const int*   wq    = (const int*)d_in[1];
  const float* bias  = (const float*)d_in[2];
  const float* scale = (const float*)d_in[3];
  const float* zp    = (const float*)d_in[4];
  float*       out   = (float*)d_out;

  const int K = 4096;
  const int N = in_sizes[1] / K;      // 4096
  const int M = in_sizes[0] / K;      // 8192

  const size_t xb_elems = (size_t)M * K;
  const size_t wb_elems = (size_t)N * K;
  const size_t need = (xb_elems + wb_elems) * sizeof(unsigned short);

  if (ws_size >= need && (M % 128 == 0) && (N % 128 == 0) && (K % 64 == 0)) {
    unsigned short* xb = (unsigned short*)d_ws;
    unsigned short* wb = xb + xb_elems;
    int nx8 = (int)(xb_elems / 8), nw8 = (int)(wb_elems / 8);
    cvt_x_kernel<<<(nx8 + 255) / 256, 256, 0, stream>>>((const f32x4*)x, (ushort8*)xb, nx8);
    cvt_w_kernel<<<(nw8 + 255) / 256, 256, 0, stream>>>((const i32x4*)wq, (ushort8*)wb, zp, nw8);
    dim3 grid((M >> 7) * (N >> 7));
    qgemm128_kernel<<<grid, 256, 0, stream>>>(xb, wb, bias, scale, out, M, N, K);
  } else {
    dim3 grid(N / 128, M / 128);
    qgemm_fused_kernel<<<grid, 256, 0, stream>>>(x, wq, bias, scale, zp, out, M, N, K);
  }
}

// Round 7
// 307.985 us; speedup vs baseline: 1.0509x; 1.0509x over previous
//
#include <hip/hip_runtime.h>
#include <stdint.h>
#include <stddef.h>

// ---------------------------------------------------------------------------
// QuantizedLinear: y = x @ (scale*(Wq - zp))^T + bias ; M=8192,N=4096,K=4096
// R7: 256x256 tile, BK=32, 8 waves (2Mx4N, wave=128x64), 4-deep LDS ring
// (4 bufs x (A 16KB + B 16KB) = 128 KiB) + CROSS-TILE REGISTER PREFETCH:
// reads for tile t+1's a_lo issued during tile t's MFMA; b/a_hi issued at
// iter top ahead of the clusters. One barrier + one counted vmcnt(4)/iter
// (never 0). Ring gives tile t+1 residency one full iter before its reads.
// Chunk-XOR swizzle (c ^= row&3) both-sides; XCD block swizzle; setprio.
// ---------------------------------------------------------------------------

typedef __attribute__((ext_vector_type(4))) float   f32x4;
typedef __attribute__((ext_vector_type(8))) short   short8;   // 8 x bf16
typedef __attribute__((ext_vector_type(4))) int     i32x4;
typedef __attribute__((ext_vector_type(8))) unsigned short ushort8;
typedef __attribute__((ext_vector_type(4))) unsigned short ushort4v;

__device__ __forceinline__ unsigned short f2bf(float f) {
  union { float f; unsigned u; } v; v.f = f;
  unsigned u = v.u;
  u += 0x7fffu + ((u >> 16) & 1u);      // RNE to bf16
  return (unsigned short)(u >> 16);
}

__device__ __forceinline__ void gld_lds16(const void* g, void* l) {
  __builtin_amdgcn_global_load_lds(
      (const __attribute__((address_space(1))) unsigned int*)g,
      (__attribute__((address_space(3))) unsigned int*)l,
      16, 0, 0);
}

__device__ __forceinline__ unsigned ldsAddr(const void* p) {
  return (unsigned)(size_t)(const __attribute__((address_space(3))) void*)p;
}

__device__ __forceinline__ void wgb() {
  asm volatile("" ::: "memory");
  __builtin_amdgcn_s_barrier();
  asm volatile("" ::: "memory");
}

#define DSR(dst, addr, OFF) \
  asm volatile("ds_read_b128 %0, %1 offset:" #OFF : "=v"(dst) : "v"(addr))
#define LGKM(N) do { asm volatile("s_waitcnt lgkmcnt(" #N ")" ::: "memory"); \
                     __builtin_amdgcn_sched_barrier(0); } while (0)
#define VMCNT(N) asm volatile("s_waitcnt vmcnt(" #N ")" ::: "memory")

// ---------- prepass: x fp32 -> bf16 ----------
__global__ __launch_bounds__(256) void cvt_x_kernel(
    const f32x4* __restrict__ x, ushort8* __restrict__ o, int n8) {
  int i = blockIdx.x * 256 + threadIdx.x;
  if (i >= n8) return;
  f32x4 a = x[2 * i], b = x[2 * i + 1];
  ushort8 r;
  r[0] = f2bf(a[0]); r[1] = f2bf(a[1]); r[2] = f2bf(a[2]); r[3] = f2bf(a[3]);
  r[4] = f2bf(b[0]); r[5] = f2bf(b[1]); r[6] = f2bf(b[2]); r[7] = f2bf(b[3]);
  o[i] = r;
}

// ---------- prepass: Wq int32 -> bf16 of (q - zp) ----------
__global__ __launch_bounds__(256) void cvt_w_kernel(
    const i32x4* __restrict__ q, ushort8* __restrict__ o,
    const float* __restrict__ zp_p, int n8) {
  int i = blockIdx.x * 256 + threadIdx.x;
  if (i >= n8) return;
  float zp = zp_p[0];
  i32x4 a = q[2 * i], b = q[2 * i + 1];
  ushort8 r;
  r[0] = f2bf((float)a[0] - zp); r[1] = f2bf((float)a[1] - zp);
  r[2] = f2bf((float)a[2] - zp); r[3] = f2bf((float)a[3] - zp);
  r[4] = f2bf((float)b[0] - zp); r[5] = f2bf((float)b[1] - zp);
  r[6] = f2bf((float)b[2] - zp); r[7] = f2bf((float)b[3] - zp);
  o[i] = r;
}

// ---------------------------------------------------------------------------
// Main 256^2 GEMM: 4-buf ring, BK=32, register-prefetch pipeline.
// LDS buf (per operand): [256 rows][32 k] bf16 = 16 KiB; 4 chunks/row;
// logical chunk c of row r stored at position c ^ (r&3) (2-way residual
// bank aliasing = free). Staged linearly; source pre-swizzled (rule #21).
// ---------------------------------------------------------------------------
__global__ __launch_bounds__(512, 2) void qgemm256_kernel(
    const unsigned short* __restrict__ A,   // [M][K] bf16 (x)
    const unsigned short* __restrict__ B,   // [N][K] bf16 (dequant W)
    const float* __restrict__ bias, const float* __restrict__ scale_p,
    float* __restrict__ C, int M, int N, int K) {
  __shared__ __attribute__((aligned(16))) unsigned short sA[4 * 8192];  // 64 KiB
  __shared__ __attribute__((aligned(16))) unsigned short sB[4 * 8192];  // 64 KiB

  const int tid  = threadIdx.x;
  const int lane = tid & 63;
  const int w    = tid >> 6;         // 0..7
  const int wr   = w >> 2;           // 0..1  (M strip of 128)
  const int wc   = w & 3;            // 0..3  (N strip of 64)

  // XCD-aware block swizzle (bijective when nwg % 8 == 0)
  const int nwg = gridDim.x;
  const int bid = blockIdx.x;
  const int swz = ((nwg & 7) == 0) ? ((bid & 7) * (nwg >> 3) + (bid >> 3)) : bid;
  const int ntn = N >> 8;
  const int bm0 = (swz / ntn) << 8;
  const int bn0 = (swz % ntn) << 8;

  const int l16 = lane & 15;
  const int l4  = lane >> 4;                     // 0..3 -> k chunk
  const unsigned swzc = (unsigned)((l4 ^ (l16 & 3)) << 4);

  // per-lane LDS read byte bases within a 16 KiB buf (row stride 64 B)
  const unsigned aBase = (unsigned)((wr * 128 + l16) * 64) + swzc;
  const unsigned bBase = (unsigned)((wc * 64 + l16) * 64) + swzc;
  const unsigned sAaddr = ldsAddr(sA);
  const unsigned sBaddr = ldsAddr(sB);

  // staging: 1024 chunks/operand/tile; thread covers ids tid and tid+512
  // row = id>>2, stored pos = id&3, src chunk = pos ^ (row&3)
  const size_t rK0 = (size_t)(tid >> 2) * K;
  const size_t rK1 = rK0 + (size_t)128 * K;
  const int srcoff = (((tid & 3) ^ ((tid >> 2) & 3)) << 3);  // src k-elems

  const unsigned short* Ab = A + (size_t)bm0 * K;
  const unsigned short* Bb = B + (size_t)bn0 * K;

  f32x4 acc[8][4] = {};
  const int nkt = K >> 5;

#define STAGE(T) do {                                                   \
    const int _bf = (T) & 3; const int _k = (T) << 5;                   \
    unsigned short* _dA = sA + (_bf << 13);                             \
    unsigned short* _dB = sB + (_bf << 13);                             \
    gld_lds16(Ab + rK0 + _k + srcoff, _dA + (tid << 3));                \
    gld_lds16(Ab + rK1 + _k + srcoff, _dA + ((tid + 512) << 3));        \
    gld_lds16(Bb + rK0 + _k + srcoff, _dB + (tid << 3));                \
    gld_lds16(Bb + rK1 + _k + srcoff, _dB + ((tid + 512) << 3));        \
  } while (0)

#define DSRB4(BUF) do { unsigned _b = sBaddr + ((unsigned)(BUF) << 14) + bBase; \
    DSR(b[0], _b, 0); DSR(b[1], _b, 1024); DSR(b[2], _b, 2048); DSR(b[3], _b, 3072); } while (0)
#define DSRA4H(BUF) do { unsigned _a = sAaddr + ((unsigned)(BUF) << 14) + aBase; \
    DSR(a2[0], _a, 4096); DSR(a2[1], _a, 5120); DSR(a2[2], _a, 6144); DSR(a2[3], _a, 7168); } while (0)
#define DSRA4L(R, BUF) do { unsigned _a = sAaddr + ((unsigned)(BUF) << 14) + aBase; \
    DSR(R[0], _a, 0); DSR(R[1], _a, 1024); DSR(R[2], _a, 2048); DSR(R[3], _a, 3072); } while (0)

#define MM16LO(AC) do { __builtin_amdgcn_s_setprio(1);                         \
    _Pragma("unroll") for (int m = 0; m < 4; ++m)                              \
    _Pragma("unroll") for (int n = 0; n < 4; ++n)                              \
      acc[m][n] = __builtin_amdgcn_mfma_f32_16x16x32_bf16(AC[m], b[n], acc[m][n], 0, 0, 0); \
    __builtin_amdgcn_s_setprio(0); } while (0)
#define MM16HI() do { __builtin_amdgcn_s_setprio(1);                           \
    _Pragma("unroll") for (int m = 0; m < 4; ++m)                              \
    _Pragma("unroll") for (int n = 0; n < 4; ++n)                              \
      acc[4 + m][n] = __builtin_amdgcn_mfma_f32_16x16x32_bf16(a2[m], b[n], acc[4 + m][n], 0, 0, 0); \
    __builtin_amdgcn_s_setprio(0); } while (0)

  // one K-sub-iteration; ACUR = prefetched a_lo for tile KT; ANXT = prefetch dest
#define KITER(KT, ACUR, ANXT) do {                                      \
    const int _c = (KT) & 3;                                            \
    const bool _p1 = (KT) + 1 < nkt, _p3 = (KT) + 3 < nkt;              \
    DSRB4(_c);                                                          \
    DSRA4H(_c);                                                         \
    if (_p3) STAGE((KT) + 3);                                           \
    LGKM(4);              /* ACUR + b resident (FIFO; a2 remain) */     \
    MM16LO(ACUR);                                                       \
    if (_p1) { DSRA4L(ANXT, ((KT) + 1) & 3); LGKM(4); }                 \
    else     { LGKM(0); }                                               \
    MM16HI();                                                           \
    if (_p3)      { VMCNT(4); wgb(); }                                  \
    else if (_p1) { VMCNT(0); wgb(); }                                  \
  } while (0)

  short8 aX[4], aY[4], b[4], a2[4];

  // ---- prologue: stage tiles 0..2; tiles 0,1 resident; prefetch a_lo(0) ----
  STAGE(0);
  if (nkt > 1) STAGE(1);
  if (nkt > 2) STAGE(2);
  if (nkt > 2) { VMCNT(4); } else { VMCNT(0); }
  wgb();
  DSRA4L(aX, 0);

  for (int kt = 0; kt < nkt; kt += 2) {
    KITER(kt, aX, aY);
    KITER(kt + 1, aY, aX);
  }
#undef KITER
#undef MM16HI
#undef MM16LO
#undef DSRA4L
#undef DSRA4H
#undef DSRB4
#undef STAGE

  // ---- epilogue: y = scale*acc + bias ----
  const float s = scale_p[0];
#pragma unroll
  for (int nf = 0; nf < 4; ++nf) {
    const int col = bn0 + wc * 64 + nf * 16 + l16;
    const float bv = bias[col];
#pragma unroll
    for (int mf = 0; mf < 8; ++mf) {
      const int row0 = bm0 + wr * 128 + mf * 16 + (l4 << 2);
#pragma unroll
      for (int j = 0; j < 4; ++j)
        C[(size_t)(row0 + j) * N + col] = fmaf(s, acc[mf][nf][j], bv);
    }
  }
}

// ---------------------------------------------------------------------------
// Fallback (no workspace): R1's fused 128^2 kernel.
// ---------------------------------------------------------------------------
__global__ __launch_bounds__(256) void qgemm_fused_kernel(
    const float* __restrict__ A, const int* __restrict__ B,
    const float* __restrict__ bias, const float* __restrict__ scale_p,
    const float* __restrict__ zp_p, float* __restrict__ C,
    int M, int N, int K) {
  constexpr int BK = 32;
  __shared__ unsigned short sAf[128 * BK];
  __shared__ unsigned short sBf[128 * BK];
  const int tid = threadIdx.x, lane = tid & 63, w = tid >> 6;
  const int wr = w >> 1, wc = w & 1;
  const int bm0 = blockIdx.y * 128, bn0 = blockIdx.x * 128;
  const int l16 = lane & 15, lk = (lane >> 4) << 3;
  const float zp = zp_p[0];
  f32x4 acc[4][4] = {};
  for (int k0 = 0; k0 < K; k0 += BK) {
#pragma unroll
    for (int c = 0; c < 4; ++c) {
      int ch = c * 256 + tid;
      int row = ch >> 3, c4 = (ch & 7) << 2;
      f32x4 av = *(const f32x4*)(A + (size_t)(bm0 + row) * K + k0 + c4);
      i32x4 bv = *(const i32x4*)(B + (size_t)(bn0 + row) * K + k0 + c4);
      ushort4v ra, rb;
      ra[0] = f2bf(av[0]); ra[1] = f2bf(av[1]); ra[2] = f2bf(av[2]); ra[3] = f2bf(av[3]);
      rb[0] = f2bf((float)bv[0] - zp); rb[1] = f2bf((float)bv[1] - zp);
      rb[2] = f2bf((float)bv[2] - zp); rb[3] = f2bf((float)bv[3] - zp);
      *(ushort4v*)&sAf[row * BK + c4] = ra;
      *(ushort4v*)&sBf[row * BK + c4] = rb;
    }
    __syncthreads();
    short8 a[4], b[4];
#pragma unroll
    for (int m = 0; m < 4; ++m) a[m] = *(const short8*)&sAf[(wr * 64 + m * 16 + l16) * BK + lk];
#pragma unroll
    for (int n = 0; n < 4; ++n) b[n] = *(const short8*)&sBf[(wc * 64 + n * 16 + l16) * BK + lk];
#pragma unroll
    for (int m = 0; m < 4; ++m)
#pragma unroll
      for (int n = 0; n < 4; ++n)
        acc[m][n] = __builtin_amdgcn_mfma_f32_16x16x32_bf16(a[m], b[n], acc[m][n], 0, 0, 0);
    __syncthreads();
  }
  const float s = scale_p[0];
#pragma unroll
  for (int n = 0; n < 4; ++n) {
    const int col = bn0 + wc * 64 + n * 16 + l16;
    const float bv = bias[col];
#pragma unroll
    for (int m = 0; m < 4; ++m) {
      const int row0 = bm0 + wr * 64 + m * 16 + ((lane >> 4) << 2);
#pragma unroll
      for (int j = 0; j < 4; ++j)
        C[(size_t)(row0 + j) * N + col] = fmaf(s, acc[m][n][j], bv);
    }
  }
}

extern "C" void kernel_launch(void* const* d_in, const int* in_sizes, int n_in,
                              void* d_out, int out_size, void* d_ws, size_t ws_size,
                              hipStream_t stream) {
  const float* x     = (const float*)d_in[0];
  const int*   wq    = (const int*)d_in[1];
  const float* bias  = (const float*)d_in[2];
  const float* scale = (const float*)d_in[3];
  const float* zp    = (const float*)d_in[4];
  float*       out   = (float*)d_out;

  const int K = 4096;
  const int N = in_sizes[1] / K;      // 4096
  const int M = in_sizes[0] / K;      // 8192

  const size_t xb_elems = (size_t)M * K;
  const size_t wb_elems = (size_t)N * K;
  const size_t need = (xb_elems + wb_elems) * sizeof(unsigned short);

  if (ws_size >= need && (M % 256 == 0) && (N % 256 == 0) && (K % 64 == 0)) {
    unsigned short* xb = (unsigned short*)d_ws;
    unsigned short* wb = xb + xb_elems;
    int nx8 = (int)(xb_elems / 8), nw8 = (int)(wb_elems / 8);
    cvt_x_kernel<<<(nx8 + 255) / 256, 256, 0, stream>>>((const f32x4*)x, (ushort8*)xb, nx8);
    cvt_w_kernel<<<(nw8 + 255) / 256, 256, 0, stream>>>((const i32x4*)wq, (ushort8*)wb, zp, nw8);
    dim3 grid((M >> 8) * (N >> 8));
    qgemm256_kernel<<<grid, 512, 0, stream>>>(xb, wb, bias, scale, out, M, N, K);
  } else {
    dim3 grid(N / 128, M / 128);
    qgemm_fused_kernel<<<grid, 256, 0, stream>>>(x, wq, bias, scale, zp, out, M, N, K);
  }
}

// Round 8
// 293.745 us; speedup vs baseline: 1.1018x; 1.0485x over previous
//
#include <hip/hip_runtime.h>
#include <stdint.h>
#include <stddef.h>

// ---------------------------------------------------------------------------
// QuantizedLinear: y = x @ (scale*(Wq - zp))^T + bias ; M=8192,N=4096,K=4096
// R8: R4 base (256x256 tile, BK=64 as 2 k-halves, 8 waves 2Mx4N, dbuf LDS
// 128KiB, PROVEN zero-conflict swizzle c^=(row>>1)&3 both-sides) +
// FULL one-sub-phase-ahead register pipeline:
//   4 sub-phases/tile; each issues the NEXT sub-phase's ds_reads BEFORE its
//   own 16-MFMA cluster; counted lgkmcnt (4/8) drains reads under MFMA.
//   One barrier/tile, preceded by lgkmcnt(0) (WAR-safe) + vmcnt(0) (stage
//   issued 3 sub-phases earlier). STAGE(t+1) = 8 gld at tile start.
// ---------------------------------------------------------------------------

typedef __attribute__((ext_vector_type(4))) float   f32x4;
typedef __attribute__((ext_vector_type(8))) short   short8;   // 8 x bf16
typedef __attribute__((ext_vector_type(4))) int     i32x4;
typedef __attribute__((ext_vector_type(8))) unsigned short ushort8;
typedef __attribute__((ext_vector_type(4))) unsigned short ushort4v;

__device__ __forceinline__ unsigned short f2bf(float f) {
  union { float f; unsigned u; } v; v.f = f;
  unsigned u = v.u;
  u += 0x7fffu + ((u >> 16) & 1u);      // RNE to bf16
  return (unsigned short)(u >> 16);
}

__device__ __forceinline__ void gld_lds16(const void* g, void* l) {
  __builtin_amdgcn_global_load_lds(
      (const __attribute__((address_space(1))) unsigned int*)g,
      (__attribute__((address_space(3))) unsigned int*)l,
      16, 0, 0);
}

__device__ __forceinline__ unsigned ldsAddr(const void* p) {
  return (unsigned)(size_t)(const __attribute__((address_space(3))) void*)p;
}

__device__ __forceinline__ void wgb() {
  asm volatile("" ::: "memory");
  __builtin_amdgcn_s_barrier();
  asm volatile("" ::: "memory");
}

#define DSR(dst, addr, OFF) \
  asm volatile("ds_read_b128 %0, %1 offset:" #OFF : "=v"(dst) : "v"(addr))
#define LGKM(N) do { asm volatile("s_waitcnt lgkmcnt(" #N ")" ::: "memory"); \
                     __builtin_amdgcn_sched_barrier(0); } while (0)
#define VMCNT(N) asm volatile("s_waitcnt vmcnt(" #N ")" ::: "memory")

// ---------- prepass: x fp32 -> bf16 ----------
__global__ __launch_bounds__(256) void cvt_x_kernel(
    const f32x4* __restrict__ x, ushort8* __restrict__ o, int n8) {
  int i = blockIdx.x * 256 + threadIdx.x;
  if (i >= n8) return;
  f32x4 a = x[2 * i], b = x[2 * i + 1];
  ushort8 r;
  r[0] = f2bf(a[0]); r[1] = f2bf(a[1]); r[2] = f2bf(a[2]); r[3] = f2bf(a[3]);
  r[4] = f2bf(b[0]); r[5] = f2bf(b[1]); r[6] = f2bf(b[2]); r[7] = f2bf(b[3]);
  o[i] = r;
}

// ---------- prepass: Wq int32 -> bf16 of (q - zp) ----------
__global__ __launch_bounds__(256) void cvt_w_kernel(
    const i32x4* __restrict__ q, ushort8* __restrict__ o,
    const float* __restrict__ zp_p, int n8) {
  int i = blockIdx.x * 256 + threadIdx.x;
  if (i >= n8) return;
  float zp = zp_p[0];
  i32x4 a = q[2 * i], b = q[2 * i + 1];
  ushort8 r;
  r[0] = f2bf((float)a[0] - zp); r[1] = f2bf((float)a[1] - zp);
  r[2] = f2bf((float)a[2] - zp); r[3] = f2bf((float)a[3] - zp);
  r[4] = f2bf((float)b[0] - zp); r[5] = f2bf((float)b[1] - zp);
  r[6] = f2bf((float)b[2] - zp); r[7] = f2bf((float)b[3] - zp);
  o[i] = r;
}

// ---------------------------------------------------------------------------
// Main 256^2 GEMM, sub-phase register pipeline.
// LDS region (buf,kh): [256 rows][32 k] bf16 = 16 KiB (4 regions); staged
// linearly; logical chunk c of row r stored at position c ^ ((r>>1)&3).
// ---------------------------------------------------------------------------
__global__ __launch_bounds__(512, 2) void qgemm256_kernel(
    const unsigned short* __restrict__ A,   // [M][K] bf16 (x)
    const unsigned short* __restrict__ B,   // [N][K] bf16 (dequant W)
    const float* __restrict__ bias, const float* __restrict__ scale_p,
    float* __restrict__ C, int M, int N, int K) {
  __shared__ __attribute__((aligned(16))) unsigned short sA[2 * 2 * 8192];
  __shared__ __attribute__((aligned(16))) unsigned short sB[2 * 2 * 8192];

  const int tid  = threadIdx.x;
  const int lane = tid & 63;
  const int w    = tid >> 6;         // 0..7
  const int wr   = w >> 2;           // 0..1  (M strip of 128)
  const int wc   = w & 3;            // 0..3  (N strip of 64)

  // XCD-aware block swizzle (bijective when nwg % 8 == 0)
  const int nwg = gridDim.x;
  const int bid = blockIdx.x;
  const int swz = ((nwg & 7) == 0) ? ((bid & 7) * (nwg >> 3) + (bid >> 3)) : bid;
  const int ntn = N >> 8;
  const int bm0 = (swz / ntn) << 8;
  const int bn0 = (swz % ntn) << 8;

  const int l16 = lane & 15;
  const int l4  = lane >> 4;                       // 0..3 -> k chunk
  const int rchk = (l4 ^ ((l16 >> 1) & 3)) << 4;   // swizzled chunk byte off (R4-proven)

  // per-lane LDS read byte bases within a 16 KiB (buf,kh) region
  const unsigned aBase = (unsigned)((wr * 128 + l16) * 64 + rchk);
  const unsigned bBase = (unsigned)((wc * 64 + l16) * 64 + rchk);
  const unsigned sAaddr = ldsAddr(sA);
  const unsigned sBaddr = ldsAddr(sB);

  // staging: thread covers rows (tid>>2) and (tid>>2)+128, one 16B chunk
  const int    st0  = tid, st1 = tid + 512;
  const size_t rK0  = (size_t)(tid >> 2) * K;
  const size_t rK1  = (size_t)((tid >> 2) + 128) * K;
  const int    csrc = ((tid & 3) ^ ((tid >> 3) & 3)) << 3;  // swizzled src k-elems

  const unsigned short* Ab = A + (size_t)bm0 * K;
  const unsigned short* Bb = B + (size_t)bn0 * K;

  f32x4 acc[8][4] = {};
  const int nkt = K >> 6;

  // STAGE(T): all 4 regions of tile T (8 gld)
#define STAGE(T) do {                                                    \
    const int _nx = (T) & 1; const int _k = (T) << 6;                    \
    unsigned short* _dA0 = sA + (((_nx << 1) + 0) << 13);                \
    unsigned short* _dA1 = sA + (((_nx << 1) + 1) << 13);                \
    unsigned short* _dB0 = sB + (((_nx << 1) + 0) << 13);                \
    unsigned short* _dB1 = sB + (((_nx << 1) + 1) << 13);                \
    gld_lds16(Ab + rK0 + _k + csrc,      _dA0 + (st0 << 3));             \
    gld_lds16(Ab + rK1 + _k + csrc,      _dA0 + (st1 << 3));             \
    gld_lds16(Ab + rK0 + _k + 32 + csrc, _dA1 + (st0 << 3));             \
    gld_lds16(Ab + rK1 + _k + 32 + csrc, _dA1 + (st1 << 3));             \
    gld_lds16(Bb + rK0 + _k + csrc,      _dB0 + (st0 << 3));             \
    gld_lds16(Bb + rK1 + _k + csrc,      _dB0 + (st1 << 3));             \
    gld_lds16(Bb + rK0 + _k + 32 + csrc, _dB1 + (st0 << 3));             \
    gld_lds16(Bb + rK1 + _k + 32 + csrc, _dB1 + (st1 << 3));             \
  } while (0)

  // issue a-lo (m0-3) + b fragments of region RG into sets AS/BS (8 DSR)
#define ISSUE_AB(AS, BS, RG) do {                                        \
    unsigned _a = sAaddr + ((unsigned)(RG) << 14) + aBase;               \
    unsigned _b = sBaddr + ((unsigned)(RG) << 14) + bBase;               \
    DSR(AS[0], _a, 0); DSR(AS[1], _a, 1024);                             \
    DSR(AS[2], _a, 2048); DSR(AS[3], _a, 3072);                          \
    DSR(BS[0], _b, 0); DSR(BS[1], _b, 1024);                             \
    DSR(BS[2], _b, 2048); DSR(BS[3], _b, 3072);                          \
  } while (0)

  // issue a-hi (m4-7) of region RG into a2 (4 DSR)
#define ISSUE_A2(RG) do {                                                \
    unsigned _a = sAaddr + ((unsigned)(RG) << 14) + aBase;               \
    DSR(a2[0], _a, 4096); DSR(a2[1], _a, 5120);                          \
    DSR(a2[2], _a, 6144); DSR(a2[3], _a, 7168);                          \
  } while (0)

#define MMLO(AS, BS) do { __builtin_amdgcn_s_setprio(1);                       \
    _Pragma("unroll") for (int m = 0; m < 4; ++m)                              \
    _Pragma("unroll") for (int n = 0; n < 4; ++n)                              \
      acc[m][n] = __builtin_amdgcn_mfma_f32_16x16x32_bf16(AS[m], BS[n], acc[m][n], 0, 0, 0); \
    __builtin_amdgcn_s_setprio(0); } while (0)
#define MMHI(BS) do { __builtin_amdgcn_s_setprio(1);                           \
    _Pragma("unroll") for (int m = 0; m < 4; ++m)                              \
    _Pragma("unroll") for (int n = 0; n < 4; ++n)                              \
      acc[4 + m][n] = __builtin_amdgcn_mfma_f32_16x16x32_bf16(a2[m], BS[n], acc[4 + m][n], 0, 0, 0); \
    __builtin_amdgcn_s_setprio(0); } while (0)

  short8 aX[4], bX[4], aY[4], bY[4], a2[4];

  // ---- prologue: stage tile0; issue ab(0,kh0) into X ----
  STAGE(0);
  VMCNT(0);
  wgb();
  ISSUE_AB(aX, bX, 0);

  for (int kt = 0; kt < nkt; ++kt) {
    const int cur = kt & 1;
    const int rg0 = cur << 1, rg1 = rg0 + 1;
    const int nrg0 = (cur ^ 1) << 1;
    const bool pf = (kt + 1 < nkt);

    // ---- kh0.P0: prefetch a2(kh0); stage t+1; MFMA lo(kh0) ----
    ISSUE_A2(rg0);                 // outstanding: abX 8 + a2 4 = 12
    if (pf) STAGE(kt + 1);         // 8 gld (vmcnt only)
    LGKM(4);                       // abX resident; a2 drains under MFMA
    MMLO(aX, bX);

    // ---- kh0.P1: prefetch ab(kh1) into Y; MFMA hi(kh0) ----
    ISSUE_AB(aY, bY, rg1);         // outstanding: a2 4 + abY 8 = 12
    LGKM(8);                       // a2 resident; abY drains under MFMA
    MMHI(bX);

    // ---- kh1.P0: prefetch a2(kh1); MFMA lo(kh1) ----
    ISSUE_A2(rg1);                 // outstanding: abY 8 + a2 4 = 12
    LGKM(4);                       // abY resident
    MMLO(aY, bY);

    // ---- kh1.P1: tile boundary; MFMA hi(kh1) ----
    if (pf) {
      LGKM(0);                     // all own reads done (incl. a2) -> WAR-safe
      VMCNT(0);                    // tile t+1 resident (staged 3 sub-phases ago)
      wgb();                       // cross-wave visibility
      ISSUE_AB(aX, bX, nrg0);      // prefetch (t+1, kh0) across the MFMA
    } else {
      LGKM(0);
    }
    MMHI(bY);
  }
#undef MMHI
#undef MMLO
#undef ISSUE_A2
#undef ISSUE_AB
#undef STAGE

  // ---- epilogue: y = scale*acc + bias ----
  const float s = scale_p[0];
#pragma unroll
  for (int nf = 0; nf < 4; ++nf) {
    const int col = bn0 + wc * 64 + nf * 16 + l16;
    const float bv = bias[col];
#pragma unroll
    for (int mf = 0; mf < 8; ++mf) {
      const int row0 = bm0 + wr * 128 + mf * 16 + (l4 << 2);
#pragma unroll
      for (int j = 0; j < 4; ++j)
        C[(size_t)(row0 + j) * N + col] = fmaf(s, acc[mf][nf][j], bv);
    }
  }
}

// ---------------------------------------------------------------------------
// Fallback (no workspace): R1's fused 128^2 kernel.
// ---------------------------------------------------------------------------
__global__ __launch_bounds__(256) void qgemm_fused_kernel(
    const float* __restrict__ A, const int* __restrict__ B,
    const float* __restrict__ bias, const float* __restrict__ scale_p,
    const float* __restrict__ zp_p, float* __restrict__ C,
    int M, int N, int K) {
  constexpr int BK = 32;
  __shared__ unsigned short sAf[128 * BK];
  __shared__ unsigned short sBf[128 * BK];
  const int tid = threadIdx.x, lane = tid & 63, w = tid >> 6;
  const int wr = w >> 1, wc = w & 1;
  const int bm0 = blockIdx.y * 128, bn0 = blockIdx.x * 128;
  const int l16 = lane & 15, lk = (lane >> 4) << 3;
  const float zp = zp_p[0];
  f32x4 acc[4][4] = {};
  for (int k0 = 0; k0 < K; k0 += BK) {
#pragma unroll
    for (int c = 0; c < 4; ++c) {
      int ch = c * 256 + tid;
      int row = ch >> 3, c4 = (ch & 7) << 2;
      f32x4 av = *(const f32x4*)(A + (size_t)(bm0 + row) * K + k0 + c4);
      i32x4 bv = *(const i32x4*)(B + (size_t)(bn0 + row) * K + k0 + c4);
      ushort4v ra, rb;
      ra[0] = f2bf(av[0]); ra[1] = f2bf(av[1]); ra[2] = f2bf(av[2]); ra[3] = f2bf(av[3]);
      rb[0] = f2bf((float)bv[0] - zp); rb[1] = f2bf((float)bv[1] - zp);
      rb[2] = f2bf((float)bv[2] - zp); rb[3] = f2bf((float)bv[3] - zp);
      *(ushort4v*)&sAf[row * BK + c4] = ra;
      *(ushort4v*)&sBf[row * BK + c4] = rb;
    }
    __syncthreads();
    short8 a[4], b[4];
#pragma unroll
    for (int m = 0; m < 4; ++m) a[m] = *(const short8*)&sAf[(wr * 64 + m * 16 + l16) * BK + lk];
#pragma unroll
    for (int n = 0; n < 4; ++n) b[n] = *(const short8*)&sBf[(wc * 64 + n * 16 + l16) * BK + lk];
#pragma unroll
    for (int m = 0; m < 4; ++m)
#pragma unroll
      for (int n = 0; n < 4; ++n)
        acc[m][n] = __builtin_amdgcn_mfma_f32_16x16x32_bf16(a[m], b[n], acc[m][n], 0, 0, 0);
    __syncthreads();
  }
  const float s = scale_p[0];
#pragma unroll
  for (int n = 0; n < 4; ++n) {
    const int col = bn0 + wc * 64 + n * 16 + l16;
    const float bv = bias[col];
#pragma unroll
    for (int m = 0; m < 4; ++m) {
      const int row0 = bm0 + wr * 64 + m * 16 + ((lane >> 4) << 2);
#pragma unroll
      for (int j = 0; j < 4; ++j)
        C[(size_t)(row0 + j) * N + col] = fmaf(s, acc[m][n][j], bv);
    }
  }
}

extern "C" void kernel_launch(void* const* d_in, const int* in_sizes, int n_in,
                              void* d_out, int out_size, void* d_ws, size_t ws_size,
                              hipStream_t stream) {
  const float* x     = (const float*)d_in[0];
  const int*   wq    = (const int*)d_in[1];
  const float* bias  = (const float*)d_in[2];
  const float* scale = (const float*)d_in[3];
  const float* zp    = (const float*)d_in[4];
  float*       out   = (float*)d_out;

  const int K = 4096;
  const int N = in_sizes[1] / K;      // 4096
  const int M = in_sizes[0] / K;      // 8192

  const size_t xb_elems = (size_t)M * K;
  const size_t wb_elems = (size_t)N * K;
  const size_t need = (xb_elems + wb_elems) * sizeof(unsigned short);

  if (ws_size >= need && (M % 256 == 0) && (N % 256 == 0) && (K % 64 == 0)) {
    unsigned short* xb = (unsigned short*)d_ws;
    unsigned short* wb = xb + xb_elems;
    int nx8 = (int)(xb_elems / 8), nw8 = (int)(wb_elems / 8);
    cvt_x_kernel<<<(nx8 + 255) / 256, 256, 0, stream>>>((const f32x4*)x, (ushort8*)xb, nx8);
    cvt_w_kernel<<<(nw8 + 255) / 256, 256, 0, stream>>>((const i32x4*)wq, (ushort8*)wb, zp, nw8);
    dim3 grid((M >> 8) * (N >> 8));
    qgemm256_kernel<<<grid, 512, 0, stream>>>(xb, wb, bias, scale, out, M, N, K);
  } else {
    dim3 grid(N / 128, M / 128);
    qgemm_fused_kernel<<<grid, 256, 0, stream>>>(x, wq, bias, scale, zp, out, M, N, K);
  }
}